// Round 10
// baseline (2893.909 us; speedup 1.0000x reference)
//
#include <hip/hip_runtime.h>

#define NN 100000

// ================= degree count (int) =================
__global__ __launch_bounds__(256) void count_kernel(const int* __restrict__ src,
                                                    const int* __restrict__ dst,
                                                    int* degO, int* degI, int E) {
    int e = blockIdx.x * 256 + threadIdx.x;
    if (e < E) {
        atomicAdd(&degO[src[e]], 1);
        atomicAdd(&degI[dst[e]], 1);
    }
}

__global__ __launch_bounds__(256) void norm_kernel(const int* __restrict__ degO,
                                                   const int* __restrict__ degI,
                                                   float* no, float* ni, int N) {
    int i = blockIdx.x * 256 + threadIdx.x;
    if (i < N) {
        no[i] = rsqrtf(fmaxf((float)degO[i], 1.0f));
        ni[i] = rsqrtf(fmaxf((float)degI[i], 1.0f));
    }
}

// ================= exclusive scan of degI -> row_start (3-phase) =================
__global__ __launch_bounds__(256) void scan1_kernel(const int* __restrict__ deg,
                                                    int* exsc, int* partials, int N) {
    __shared__ int sh[256];
    int i = blockIdx.x * 256 + threadIdx.x;
    int v = (i < N) ? deg[i] : 0;
    sh[threadIdx.x] = v;
    __syncthreads();
    for (int off = 1; off < 256; off <<= 1) {
        int t = (threadIdx.x >= off) ? sh[threadIdx.x - off] : 0;
        __syncthreads();
        sh[threadIdx.x] += t;
        __syncthreads();
    }
    if (i < N) exsc[i] = sh[threadIdx.x] - v;
    if (threadIdx.x == 255) partials[blockIdx.x] = sh[255];
}

__global__ __launch_bounds__(512) void scan2_kernel(int* partials, int nb) {
    __shared__ int sh[512];
    int v = (threadIdx.x < nb) ? partials[threadIdx.x] : 0;
    sh[threadIdx.x] = v;
    __syncthreads();
    for (int off = 1; off < 512; off <<= 1) {
        int t = (threadIdx.x >= off) ? sh[threadIdx.x - off] : 0;
        __syncthreads();
        sh[threadIdx.x] += t;
        __syncthreads();
    }
    if (threadIdx.x < nb) partials[threadIdx.x] = sh[threadIdx.x] - v;  // exclusive
}

__global__ __launch_bounds__(256) void scan3_kernel(int* exsc, const int* __restrict__ partials,
                                                    int* cursor, int N) {
    int i = blockIdx.x * 256 + threadIdx.x;
    if (i < N) {
        int r = exsc[i] + partials[blockIdx.x];
        exsc[i] = r;
        cursor[i] = r;
    }
}

// ================= CSR fill: csr_src[slot(dst)] = src =================
__global__ __launch_bounds__(256) void fill_kernel(const int* __restrict__ src,
                                                   const int* __restrict__ dst,
                                                   int* cursor, int* csr_src, int E) {
    int e = blockIdx.x * 256 + threadIdx.x;
    if (e < E) {
        int pos = atomicAdd(&cursor[dst[e]], 1);
        csr_src[pos] = src[e];
    }
}

// ================= gather-aggregate: out[n] = sum_{e in(n)} h[src(e)] (*no[src]) =================
template <int D4, int TPN, bool SCALE>
__global__ __launch_bounds__(256) void aggregate_kernel(const float4* __restrict__ h,
                                                        const int* __restrict__ row_start,
                                                        const int* __restrict__ deg,
                                                        const int* __restrict__ csr_src,
                                                        const float* __restrict__ no,
                                                        float4* __restrict__ out, int N) {
    int tid = blockIdx.x * 256 + threadIdx.x;
    int node = tid / TPN;
    int lane = tid % TPN;
    if (node >= N) return;
    const bool active = lane < D4;
    float4 acc = make_float4(0.f, 0.f, 0.f, 0.f);
    const int start = row_start[node];
    const int d = deg[node];
    int j = 0;
    for (; j + 1 < d; j += 2) {
        int s0 = csr_src[start + j];
        int s1 = csr_src[start + j + 1];
        if (active) {
            float4 v0 = h[(size_t)s0 * D4 + lane];
            float4 v1 = h[(size_t)s1 * D4 + lane];
            float c0 = SCALE ? no[s0] : 1.0f;
            float c1 = SCALE ? no[s1] : 1.0f;
            acc.x += v0.x * c0 + v1.x * c1;
            acc.y += v0.y * c0 + v1.y * c1;
            acc.z += v0.z * c0 + v1.z * c1;
            acc.w += v0.w * c0 + v1.w * c1;
        }
    }
    if (j < d) {
        int s0 = csr_src[start + j];
        if (active) {
            float4 v0 = h[(size_t)s0 * D4 + lane];
            float c0 = SCALE ? no[s0] : 1.0f;
            acc.x += v0.x * c0;
            acc.y += v0.y * c0;
            acc.z += v0.z * c0;
            acc.w += v0.w * c0;
        }
    }
    if (active) out[(size_t)node * D4 + lane] = acc;
}

// ====== layer-3 fused aggregate (y is N x 48 dense): out[n,c<47] = relu(agg*nin + b3) ======
template <int D4, int TPN>
__global__ __launch_bounds__(256) void aggregate_final_kernel(const float4* __restrict__ y,
                                                              const int* __restrict__ row_start,
                                                              const int* __restrict__ deg,
                                                              const int* __restrict__ csr_src,
                                                              const float* __restrict__ nin,
                                                              const float* __restrict__ b3,
                                                              float* __restrict__ out, int N) {
    int tid = blockIdx.x * 256 + threadIdx.x;
    int node = tid / TPN;
    int lane = tid % TPN;
    if (node >= N) return;
    const bool active = lane < D4;
    float4 acc = make_float4(0.f, 0.f, 0.f, 0.f);
    const int start = row_start[node];
    const int d = deg[node];
    int j = 0;
    for (; j + 1 < d; j += 2) {
        int s0 = csr_src[start + j];
        int s1 = csr_src[start + j + 1];
        if (active) {
            float4 v0 = y[(size_t)s0 * D4 + lane];
            float4 v1 = y[(size_t)s1 * D4 + lane];
            acc.x += v0.x + v1.x;
            acc.y += v0.y + v1.y;
            acc.z += v0.z + v1.z;
            acc.w += v0.w + v1.w;
        }
    }
    if (j < d) {
        int s0 = csr_src[start + j];
        if (active) {
            float4 v0 = y[(size_t)s0 * D4 + lane];
            acc.x += v0.x;
            acc.y += v0.y;
            acc.z += v0.z;
            acc.w += v0.w;
        }
    }
    if (active) {
        float s = nin[node];
        float vals[4] = {acc.x, acc.y, acc.z, acc.w};
        int c0 = lane * 4;
#pragma unroll
        for (int k = 0; k < 4; ++k) {
            int c = c0 + k;
            if (c < 47) out[(size_t)node * 47 + c] = fmaxf(vals[k] * s + b3[c], 0.0f);
        }
    }
}

// ================= GEMM: out = epi ? relu(A@W *nin + b)*nout : A@W =================
// EMPIRICAL (rounds 1/3/4): specially-shaped layer-3 instantiations scratch-spilled.
// ONLY <100,128,16> and <128,128,16> may exist; layer 3 reuses <128,128,16> with
// runtime epi=0/ostride=48 (W3 cols zero-padded via wcols=47).
// Round 10: OCCUPANCY fix. Round-7 structure (register A path, 1-deep prefetch,
// best measured 76us) + BK 64->32 (Wl 16 KB) + __launch_bounds__(256,8) (VGPR
// cap 64; r7 used 60). Blocks/CU limit 4 -> 8; grid ~6.1 blocks/CU all resident
// -> ~24 waves/CU to hide scattered-A L3 latency with TLP (ILP attempts r8/r9
// both regressed).
template <int K, int NOUTP, int TJ>
__global__ __launch_bounds__(256, 8) void gemm_kernel(const float* __restrict__ A,
                                                      const float* __restrict__ W, const int wcols,
                                                      const float* __restrict__ bias,
                                                      const float* __restrict__ nin,
                                                      const float* __restrict__ nout,
                                                      float* __restrict__ out, const int N,
                                                      const int epi, const int ostride) {
    constexpr int BK = 32;
    constexpr int ROWS = 256 / TJ;         // 16
    constexpr int M2 = 4;
    constexpr int BM = ROWS * M2;          // 64
    constexpr int NJ4 = NOUTP / (TJ * 4);  // 2
    constexpr int K4 = K / 4;
    constexpr int NCH = (K + BK - 1) / BK;

    __shared__ __align__(16) float Wl[BK * NOUTP];

    const int tid = threadIdx.x;
    const int tj = tid % TJ;
    const int r = tid / TJ;
    const int n0 = blockIdx.x * BM + r * M2;

    // clamped row pointers: invalid rows read row N-1 (garbage acc, never stored)
    const float4* pA[M2];
#pragma unroll
    for (int m = 0; m < M2; ++m) {
        int rm = n0 + m;
        rm = (rm < N) ? rm : (N - 1);
        pA[m] = (const float4*)A + (size_t)rm * K4;
    }

    float acc[M2][NJ4 * 4];
#pragma unroll
    for (int m = 0; m < M2; ++m)
#pragma unroll
        for (int j = 0; j < NJ4 * 4; ++j) acc[m][j] = 0.0f;

    // 1-deep register prefetch of A
    float4 an[M2];
#pragma unroll
    for (int m = 0; m < M2; ++m) an[m] = pA[m][0];

    for (int ch = 0; ch < NCH; ++ch) {
        const int k0 = ch * BK;
        const int L = (K - k0 < BK) ? (K - k0) : BK;
        if (wcols == NOUTP) {
            const float4* W4 = (const float4*)(W + (size_t)k0 * NOUTP);
            float4* Wl4 = (float4*)Wl;
            for (int i = tid; i < L * NOUTP / 4; i += 256) Wl4[i] = W4[i];
        } else {
            for (int i = tid; i < L * NOUTP; i += 256) {
                int k = i / NOUTP;
                int c = i - k * NOUTP;
                Wl[i] = (c < wcols) ? W[(size_t)(k0 + k) * wcols + c] : 0.0f;
            }
        }
        __syncthreads();

        const int L4 = L / 4;
        for (int k4 = 0; k4 < L4; ++k4) {
            float af[M2][4];
#pragma unroll
            for (int m = 0; m < M2; ++m) {
                af[m][0] = an[m].x; af[m][1] = an[m].y;
                af[m][2] = an[m].z; af[m][3] = an[m].w;
            }
            const int nk = k0 / 4 + k4 + 1;     // next global k4 (crosses chunk boundary)
            if (nk < K4) {
#pragma unroll
                for (int m = 0; m < M2; ++m) an[m] = pA[m][nk];
            }
#pragma unroll
            for (int kk = 0; kk < 4; ++kk) {
#pragma unroll
                for (int jj = 0; jj < NJ4; ++jj) {
                    const float4 w = *(const float4*)&Wl[(k4 * 4 + kk) * NOUTP + (jj * TJ + tj) * 4];
#pragma unroll
                    for (int m = 0; m < M2; ++m) {
                        acc[m][jj * 4 + 0] = fmaf(af[m][kk], w.x, acc[m][jj * 4 + 0]);
                        acc[m][jj * 4 + 1] = fmaf(af[m][kk], w.y, acc[m][jj * 4 + 1]);
                        acc[m][jj * 4 + 2] = fmaf(af[m][kk], w.z, acc[m][jj * 4 + 2]);
                        acc[m][jj * 4 + 3] = fmaf(af[m][kk], w.w, acc[m][jj * 4 + 3]);
                    }
                }
            }
        }
        __syncthreads();
    }

#pragma unroll
    for (int m = 0; m < M2; ++m) {
        const int n = n0 + m;
        if (n < N) {
            const float s_in = epi ? nin[n] : 1.0f;
            const float s_out = epi ? nout[n] : 1.0f;
#pragma unroll
            for (int jj = 0; jj < NJ4; ++jj) {
                const int c0 = (jj * TJ + tj) * 4;
                if (c0 < ostride) {
                    float v0e = acc[m][jj * 4 + 0] * s_in;
                    float v1e = acc[m][jj * 4 + 1] * s_in;
                    float v2e = acc[m][jj * 4 + 2] * s_in;
                    float v3e = acc[m][jj * 4 + 3] * s_in;
                    if (epi) {
                        v0e = fmaxf(v0e + bias[c0 + 0], 0.0f) * s_out;
                        v1e = fmaxf(v1e + bias[c0 + 1], 0.0f) * s_out;
                        v2e = fmaxf(v2e + bias[c0 + 2], 0.0f) * s_out;
                        v3e = fmaxf(v3e + bias[c0 + 3], 0.0f) * s_out;
                    }
                    float4 o = make_float4(v0e, v1e, v2e, v3e);
                    *(float4*)&out[(size_t)n * ostride + c0] = o;
                }
            }
        }
    }
}

extern "C" void kernel_launch(void* const* d_in, const int* in_sizes, int n_in,
                              void* d_out, int out_size, void* d_ws, size_t ws_size,
                              hipStream_t stream) {
    const float* x  = (const float*)d_in[0];
    const int*   ei = (const int*)d_in[1];
    const float* W1 = (const float*)d_in[2];
    const float* b1 = (const float*)d_in[3];
    const float* W2 = (const float*)d_in[4];
    const float* b2 = (const float*)d_in[5];
    const float* W3 = (const float*)d_in[6];
    const float* b3 = (const float*)d_in[7];
    float* out = (float*)d_out;

    const int N = NN;
    const int E = in_sizes[1] / 2;
    const int* src = ei;
    const int* dst = ei + E;

    // ---- workspace layout ----
    float* ws = (float*)d_ws;
    float* norm_out = ws;                       // N f
    float* norm_in  = ws + N;                   // N f
    float* bufA = ws + 2 * (size_t)N;           // N x 128 f (agg; aliased as bufY N x 48)
    float* bufB = bufA + (size_t)N * 128;       // N x 128 f (h)
    int* ip = (int*)(bufB + (size_t)N * 128);
    int* degO      = ip;                        // N i
    int* degI      = ip + N;                    // N i
    int* row_start = ip + 2 * (size_t)N;        // N i
    int* cursor    = ip + 3 * (size_t)N;        // N i
    int* csr_src   = ip + 4 * (size_t)N;        // E i
    int* partials  = csr_src + E;               // 512 i
    float* bufY = bufA;                         // N x 48 dense (layer-3 y)

    const int NB = (N + 255) / 256;             // 391 scan blocks

    // ---- degrees, norms, CSR ----
    hipMemsetAsync(degO, 0, 2 * (size_t)N * sizeof(int), stream);
    count_kernel<<<(E + 255) / 256, 256, 0, stream>>>(src, dst, degO, degI, E);
    norm_kernel<<<NB, 256, 0, stream>>>(degO, degI, norm_out, norm_in, N);
    scan1_kernel<<<NB, 256, 0, stream>>>(degI, row_start, partials, N);
    scan2_kernel<<<1, 512, 0, stream>>>(partials, NB);
    scan3_kernel<<<NB, 256, 0, stream>>>(row_start, partials, cursor, N);
    fill_kernel<<<(E + 255) / 256, 256, 0, stream>>>(src, dst, cursor, csr_src, E);

    // ---- layer 1: agg1 = gather-agg(x * no, 100); h1' = relu(agg1@W1 *nin + b1) * no ----
    aggregate_kernel<25, 32, true><<<(N * 32 + 255) / 256, 256, 0, stream>>>(
        (const float4*)x, row_start, degI, csr_src, norm_out, (float4*)bufA, N);
    gemm_kernel<100, 128, 16><<<(N + 63) / 64, 256, 0, stream>>>(
        bufA, W1, 128, b1, norm_in, norm_out, bufB, N, 1, 128);

    // ---- layer 2: agg2 = gather-agg(h1', 128); h2' = relu(agg2@W2 *nin + b2) * no ----
    aggregate_kernel<32, 32, false><<<(N * 32 + 255) / 256, 256, 0, stream>>>(
        (const float4*)bufB, row_start, degI, csr_src, nullptr, (float4*)bufA, N);
    gemm_kernel<128, 128, 16><<<(N + 63) / 64, 256, 0, stream>>>(
        bufA, W2, 128, b2, norm_in, norm_out, bufB, N, 1, 128);

    // ---- layer 3 (reordered): y = h2'@W3 — SAME instantiation as layer 2, W3 cols
    //      zero-padded 47->128, compact output stride 48; then fused final aggregate ----
    gemm_kernel<128, 128, 16><<<(N + 63) / 64, 256, 0, stream>>>(
        bufB, W3, 47, nullptr, nullptr, nullptr, bufY, N, 0, 48);
    aggregate_final_kernel<12, 16><<<(N * 16 + 255) / 256, 256, 0, stream>>>(
        (const float4*)bufY, row_start, degI, csr_src, norm_in, b3, out, N);
}

// Round 11
// 2137.988 us; speedup vs baseline: 1.3536x; 1.3536x over previous
//
#include <hip/hip_runtime.h>

#define NN 100000

// ================= degree count (int) =================
__global__ __launch_bounds__(256) void count_kernel(const int* __restrict__ src,
                                                    const int* __restrict__ dst,
                                                    int* degO, int* degI, int E) {
    int e = blockIdx.x * 256 + threadIdx.x;
    if (e < E) {
        atomicAdd(&degO[src[e]], 1);
        atomicAdd(&degI[dst[e]], 1);
    }
}

__global__ __launch_bounds__(256) void norm_kernel(const int* __restrict__ degO,
                                                   const int* __restrict__ degI,
                                                   float* no, float* ni, int N) {
    int i = blockIdx.x * 256 + threadIdx.x;
    if (i < N) {
        no[i] = rsqrtf(fmaxf((float)degO[i], 1.0f));
        ni[i] = rsqrtf(fmaxf((float)degI[i], 1.0f));
    }
}

// ================= exclusive scan of degI -> row_start (3-phase) =================
__global__ __launch_bounds__(256) void scan1_kernel(const int* __restrict__ deg,
                                                    int* exsc, int* partials, int N) {
    __shared__ int sh[256];
    int i = blockIdx.x * 256 + threadIdx.x;
    int v = (i < N) ? deg[i] : 0;
    sh[threadIdx.x] = v;
    __syncthreads();
    for (int off = 1; off < 256; off <<= 1) {
        int t = (threadIdx.x >= off) ? sh[threadIdx.x - off] : 0;
        __syncthreads();
        sh[threadIdx.x] += t;
        __syncthreads();
    }
    if (i < N) exsc[i] = sh[threadIdx.x] - v;
    if (threadIdx.x == 255) partials[blockIdx.x] = sh[255];
}

__global__ __launch_bounds__(512) void scan2_kernel(int* partials, int nb) {
    __shared__ int sh[512];
    int v = (threadIdx.x < nb) ? partials[threadIdx.x] : 0;
    sh[threadIdx.x] = v;
    __syncthreads();
    for (int off = 1; off < 512; off <<= 1) {
        int t = (threadIdx.x >= off) ? sh[threadIdx.x - off] : 0;
        __syncthreads();
        sh[threadIdx.x] += t;
        __syncthreads();
    }
    if (threadIdx.x < nb) partials[threadIdx.x] = sh[threadIdx.x] - v;  // exclusive
}

__global__ __launch_bounds__(256) void scan3_kernel(int* exsc, const int* __restrict__ partials,
                                                    int* cursor, int N) {
    int i = blockIdx.x * 256 + threadIdx.x;
    if (i < N) {
        int r = exsc[i] + partials[blockIdx.x];
        exsc[i] = r;
        cursor[i] = r;
    }
}

// ================= CSR fill: csr_src[slot(dst)] = src =================
__global__ __launch_bounds__(256) void fill_kernel(const int* __restrict__ src,
                                                   const int* __restrict__ dst,
                                                   int* cursor, int* csr_src, int E) {
    int e = blockIdx.x * 256 + threadIdx.x;
    if (e < E) {
        int pos = atomicAdd(&cursor[dst[e]], 1);
        csr_src[pos] = src[e];
    }
}

// ================= gather-aggregate: out[n] = sum_{e in(n)} h[src(e)] (*no[src]) =================
template <int D4, int TPN, bool SCALE>
__global__ __launch_bounds__(256) void aggregate_kernel(const float4* __restrict__ h,
                                                        const int* __restrict__ row_start,
                                                        const int* __restrict__ deg,
                                                        const int* __restrict__ csr_src,
                                                        const float* __restrict__ no,
                                                        float4* __restrict__ out, int N) {
    int tid = blockIdx.x * 256 + threadIdx.x;
    int node = tid / TPN;
    int lane = tid % TPN;
    if (node >= N) return;
    const bool active = lane < D4;
    float4 acc = make_float4(0.f, 0.f, 0.f, 0.f);
    const int start = row_start[node];
    const int d = deg[node];
    int j = 0;
    for (; j + 1 < d; j += 2) {
        int s0 = csr_src[start + j];
        int s1 = csr_src[start + j + 1];
        if (active) {
            float4 v0 = h[(size_t)s0 * D4 + lane];
            float4 v1 = h[(size_t)s1 * D4 + lane];
            float c0 = SCALE ? no[s0] : 1.0f;
            float c1 = SCALE ? no[s1] : 1.0f;
            acc.x += v0.x * c0 + v1.x * c1;
            acc.y += v0.y * c0 + v1.y * c1;
            acc.z += v0.z * c0 + v1.z * c1;
            acc.w += v0.w * c0 + v1.w * c1;
        }
    }
    if (j < d) {
        int s0 = csr_src[start + j];
        if (active) {
            float4 v0 = h[(size_t)s0 * D4 + lane];
            float c0 = SCALE ? no[s0] : 1.0f;
            acc.x += v0.x * c0;
            acc.y += v0.y * c0;
            acc.z += v0.z * c0;
            acc.w += v0.w * c0;
        }
    }
    if (active) out[(size_t)node * D4 + lane] = acc;
}

// ====== layer-3 fused aggregate (y is N x 48 dense): out[n,c<47] = relu(agg*nin + b3) ======
template <int D4, int TPN>
__global__ __launch_bounds__(256) void aggregate_final_kernel(const float4* __restrict__ y,
                                                              const int* __restrict__ row_start,
                                                              const int* __restrict__ deg,
                                                              const int* __restrict__ csr_src,
                                                              const float* __restrict__ nin,
                                                              const float* __restrict__ b3,
                                                              float* __restrict__ out, int N) {
    int tid = blockIdx.x * 256 + threadIdx.x;
    int node = tid / TPN;
    int lane = tid % TPN;
    if (node >= N) return;
    const bool active = lane < D4;
    float4 acc = make_float4(0.f, 0.f, 0.f, 0.f);
    const int start = row_start[node];
    const int d = deg[node];
    int j = 0;
    for (; j + 1 < d; j += 2) {
        int s0 = csr_src[start + j];
        int s1 = csr_src[start + j + 1];
        if (active) {
            float4 v0 = y[(size_t)s0 * D4 + lane];
            float4 v1 = y[(size_t)s1 * D4 + lane];
            acc.x += v0.x + v1.x;
            acc.y += v0.y + v1.y;
            acc.z += v0.z + v1.z;
            acc.w += v0.w + v1.w;
        }
    }
    if (j < d) {
        int s0 = csr_src[start + j];
        if (active) {
            float4 v0 = y[(size_t)s0 * D4 + lane];
            acc.x += v0.x;
            acc.y += v0.y;
            acc.z += v0.z;
            acc.w += v0.w;
        }
    }
    if (active) {
        float s = nin[node];
        float vals[4] = {acc.x, acc.y, acc.z, acc.w};
        int c0 = lane * 4;
#pragma unroll
        for (int k = 0; k < 4; ++k) {
            int c = c0 + k;
            if (c < 47) out[(size_t)node * 47 + c] = fmaxf(vals[k] * s + b3[c], 0.0f);
        }
    }
}

// ================= GEMM: out = epi ? relu(A@W *nin + b)*nout : A@W =================
// EMPIRICAL (rounds 1/3/4/10): spill discipline. Specially-shaped layer-3
// instantiations spilled (r1/3/4); __launch_bounds__(256,8) forced VGPR 32 and
// spilled 2.5 GB (r10). ONLY <100,128,16> and <128,128,16> may exist; layer 3
// reuses <128,128,16> with runtime epi=0/ostride=48. Launch bounds stay (256,4)
// — r7's natural 60 VGPR is already under the 64-VGPR occupancy step.
// Round 11: r7 structure (register A, 1-deep prefetch, best 76us) with BK 64->32:
// Wl 32->16 KB lifts the LDS blocks/CU limit 5->10 (VGPR allows 8) -> ~2x TLP
// to hide scattered-A L3 latency.
template <int K, int NOUTP, int TJ>
__global__ __launch_bounds__(256, 4) void gemm_kernel(const float* __restrict__ A,
                                                      const float* __restrict__ W, const int wcols,
                                                      const float* __restrict__ bias,
                                                      const float* __restrict__ nin,
                                                      const float* __restrict__ nout,
                                                      float* __restrict__ out, const int N,
                                                      const int epi, const int ostride) {
    constexpr int BK = 32;
    constexpr int ROWS = 256 / TJ;         // 16
    constexpr int M2 = 4;
    constexpr int BM = ROWS * M2;          // 64
    constexpr int NJ4 = NOUTP / (TJ * 4);  // 2
    constexpr int K4 = K / 4;
    constexpr int NCH = (K + BK - 1) / BK;

    __shared__ __align__(16) float Wl[BK * NOUTP];

    const int tid = threadIdx.x;
    const int tj = tid % TJ;
    const int r = tid / TJ;
    const int n0 = blockIdx.x * BM + r * M2;

    // clamped row pointers: invalid rows read row N-1 (garbage acc, never stored)
    const float4* pA[M2];
#pragma unroll
    for (int m = 0; m < M2; ++m) {
        int rm = n0 + m;
        rm = (rm < N) ? rm : (N - 1);
        pA[m] = (const float4*)A + (size_t)rm * K4;
    }

    float acc[M2][NJ4 * 4];
#pragma unroll
    for (int m = 0; m < M2; ++m)
#pragma unroll
        for (int j = 0; j < NJ4 * 4; ++j) acc[m][j] = 0.0f;

    // 1-deep register prefetch of A
    float4 an[M2];
#pragma unroll
    for (int m = 0; m < M2; ++m) an[m] = pA[m][0];

    for (int ch = 0; ch < NCH; ++ch) {
        const int k0 = ch * BK;
        const int L = (K - k0 < BK) ? (K - k0) : BK;
        if (wcols == NOUTP) {
            const float4* W4 = (const float4*)(W + (size_t)k0 * NOUTP);
            float4* Wl4 = (float4*)Wl;
            for (int i = tid; i < L * NOUTP / 4; i += 256) Wl4[i] = W4[i];
        } else {
            for (int i = tid; i < L * NOUTP; i += 256) {
                int k = i / NOUTP;
                int c = i - k * NOUTP;
                Wl[i] = (c < wcols) ? W[(size_t)(k0 + k) * wcols + c] : 0.0f;
            }
        }
        __syncthreads();

        const int L4 = L / 4;
        for (int k4 = 0; k4 < L4; ++k4) {
            float af[M2][4];
#pragma unroll
            for (int m = 0; m < M2; ++m) {
                af[m][0] = an[m].x; af[m][1] = an[m].y;
                af[m][2] = an[m].z; af[m][3] = an[m].w;
            }
            const int nk = k0 / 4 + k4 + 1;     // next global k4 (crosses chunk boundary)
            if (nk < K4) {
#pragma unroll
                for (int m = 0; m < M2; ++m) an[m] = pA[m][nk];
            }
#pragma unroll
            for (int kk = 0; kk < 4; ++kk) {
#pragma unroll
                for (int jj = 0; jj < NJ4; ++jj) {
                    const float4 w = *(const float4*)&Wl[(k4 * 4 + kk) * NOUTP + (jj * TJ + tj) * 4];
#pragma unroll
                    for (int m = 0; m < M2; ++m) {
                        acc[m][jj * 4 + 0] = fmaf(af[m][kk], w.x, acc[m][jj * 4 + 0]);
                        acc[m][jj * 4 + 1] = fmaf(af[m][kk], w.y, acc[m][jj * 4 + 1]);
                        acc[m][jj * 4 + 2] = fmaf(af[m][kk], w.z, acc[m][jj * 4 + 2]);
                        acc[m][jj * 4 + 3] = fmaf(af[m][kk], w.w, acc[m][jj * 4 + 3]);
                    }
                }
            }
        }
        __syncthreads();
    }

#pragma unroll
    for (int m = 0; m < M2; ++m) {
        const int n = n0 + m;
        if (n < N) {
            const float s_in = epi ? nin[n] : 1.0f;
            const float s_out = epi ? nout[n] : 1.0f;
#pragma unroll
            for (int jj = 0; jj < NJ4; ++jj) {
                const int c0 = (jj * TJ + tj) * 4;
                if (c0 < ostride) {
                    float v0e = acc[m][jj * 4 + 0] * s_in;
                    float v1e = acc[m][jj * 4 + 1] * s_in;
                    float v2e = acc[m][jj * 4 + 2] * s_in;
                    float v3e = acc[m][jj * 4 + 3] * s_in;
                    if (epi) {
                        v0e = fmaxf(v0e + bias[c0 + 0], 0.0f) * s_out;
                        v1e = fmaxf(v1e + bias[c0 + 1], 0.0f) * s_out;
                        v2e = fmaxf(v2e + bias[c0 + 2], 0.0f) * s_out;
                        v3e = fmaxf(v3e + bias[c0 + 3], 0.0f) * s_out;
                    }
                    float4 o = make_float4(v0e, v1e, v2e, v3e);
                    *(float4*)&out[(size_t)n * ostride + c0] = o;
                }
            }
        }
    }
}

extern "C" void kernel_launch(void* const* d_in, const int* in_sizes, int n_in,
                              void* d_out, int out_size, void* d_ws, size_t ws_size,
                              hipStream_t stream) {
    const float* x  = (const float*)d_in[0];
    const int*   ei = (const int*)d_in[1];
    const float* W1 = (const float*)d_in[2];
    const float* b1 = (const float*)d_in[3];
    const float* W2 = (const float*)d_in[4];
    const float* b2 = (const float*)d_in[5];
    const float* W3 = (const float*)d_in[6];
    const float* b3 = (const float*)d_in[7];
    float* out = (float*)d_out;

    const int N = NN;
    const int E = in_sizes[1] / 2;
    const int* src = ei;
    const int* dst = ei + E;

    // ---- workspace layout ----
    float* ws = (float*)d_ws;
    float* norm_out = ws;                       // N f
    float* norm_in  = ws + N;                   // N f
    float* bufA = ws + 2 * (size_t)N;           // N x 128 f (agg; aliased as bufY N x 48)
    float* bufB = bufA + (size_t)N * 128;       // N x 128 f (h)
    int* ip = (int*)(bufB + (size_t)N * 128);
    int* degO      = ip;                        // N i
    int* degI      = ip + N;                    // N i
    int* row_start = ip + 2 * (size_t)N;        // N i
    int* cursor    = ip + 3 * (size_t)N;        // N i
    int* csr_src   = ip + 4 * (size_t)N;        // E i
    int* partials  = csr_src + E;               // 512 i
    float* bufY = bufA;                         // N x 48 dense (layer-3 y)

    const int NB = (N + 255) / 256;             // 391 scan blocks

    // ---- degrees, norms, CSR ----
    hipMemsetAsync(degO, 0, 2 * (size_t)N * sizeof(int), stream);
    count_kernel<<<(E + 255) / 256, 256, 0, stream>>>(src, dst, degO, degI, E);
    norm_kernel<<<NB, 256, 0, stream>>>(degO, degI, norm_out, norm_in, N);
    scan1_kernel<<<NB, 256, 0, stream>>>(degI, row_start, partials, N);
    scan2_kernel<<<1, 512, 0, stream>>>(partials, NB);
    scan3_kernel<<<NB, 256, 0, stream>>>(row_start, partials, cursor, N);
    fill_kernel<<<(E + 255) / 256, 256, 0, stream>>>(src, dst, cursor, csr_src, E);

    // ---- layer 1: agg1 = gather-agg(x * no, 100); h1' = relu(agg1@W1 *nin + b1) * no ----
    aggregate_kernel<25, 32, true><<<(N * 32 + 255) / 256, 256, 0, stream>>>(
        (const float4*)x, row_start, degI, csr_src, norm_out, (float4*)bufA, N);
    gemm_kernel<100, 128, 16><<<(N + 63) / 64, 256, 0, stream>>>(
        bufA, W1, 128, b1, norm_in, norm_out, bufB, N, 1, 128);

    // ---- layer 2: agg2 = gather-agg(h1', 128); h2' = relu(agg2@W2 *nin + b2) * no ----
    aggregate_kernel<32, 32, false><<<(N * 32 + 255) / 256, 256, 0, stream>>>(
        (const float4*)bufB, row_start, degI, csr_src, nullptr, (float4*)bufA, N);
    gemm_kernel<128, 128, 16><<<(N + 63) / 64, 256, 0, stream>>>(
        bufA, W2, 128, b2, norm_in, norm_out, bufB, N, 1, 128);

    // ---- layer 3 (reordered): y = h2'@W3 — SAME instantiation as layer 2, W3 cols
    //      zero-padded 47->128, compact output stride 48; then fused final aggregate ----
    gemm_kernel<128, 128, 16><<<(N + 63) / 64, 256, 0, stream>>>(
        bufB, W3, 47, nullptr, nullptr, nullptr, bufY, N, 0, 48);
    aggregate_final_kernel<12, 16><<<(N * 16 + 255) / 256, 256, 0, stream>>>(
        (const float4*)bufY, row_start, degI, csr_src, norm_in, b3, out, N);
}

// Round 12
// 400.866 us; speedup vs baseline: 7.2191x; 5.3334x over previous
//
#include <hip/hip_runtime.h>

#define NN 100000

// ================= degree count (int) =================
__global__ __launch_bounds__(256) void count_kernel(const int* __restrict__ src,
                                                    const int* __restrict__ dst,
                                                    int* degO, int* degI, int E) {
    int e = blockIdx.x * 256 + threadIdx.x;
    if (e < E) {
        atomicAdd(&degO[src[e]], 1);
        atomicAdd(&degI[dst[e]], 1);
    }
}

// ================= exclusive scan of degI -> row_start (3-phase) =================
__global__ __launch_bounds__(256) void scan1_kernel(const int* __restrict__ deg,
                                                    int* exsc, int* partials, int N) {
    __shared__ int sh[256];
    int i = blockIdx.x * 256 + threadIdx.x;
    int v = (i < N) ? deg[i] : 0;
    sh[threadIdx.x] = v;
    __syncthreads();
    for (int off = 1; off < 256; off <<= 1) {
        int t = (threadIdx.x >= off) ? sh[threadIdx.x - off] : 0;
        __syncthreads();
        sh[threadIdx.x] += t;
        __syncthreads();
    }
    if (i < N) exsc[i] = sh[threadIdx.x] - v;
    if (threadIdx.x == 255) partials[blockIdx.x] = sh[255];
}

__global__ __launch_bounds__(512) void scan2_kernel(int* partials, int nb) {
    __shared__ int sh[512];
    int v = (threadIdx.x < nb) ? partials[threadIdx.x] : 0;
    sh[threadIdx.x] = v;
    __syncthreads();
    for (int off = 1; off < 512; off <<= 1) {
        int t = (threadIdx.x >= off) ? sh[threadIdx.x - off] : 0;
        __syncthreads();
        sh[threadIdx.x] += t;
        __syncthreads();
    }
    if (threadIdx.x < nb) partials[threadIdx.x] = sh[threadIdx.x] - v;  // exclusive
}

// scan3 + fused norm computation (saves a launch)
__global__ __launch_bounds__(256) void scan3_norm_kernel(int* exsc, const int* __restrict__ partials,
                                                         int* cursor,
                                                         const int* __restrict__ degO,
                                                         const int* __restrict__ degI,
                                                         float* no, float* ni, int N) {
    int i = blockIdx.x * 256 + threadIdx.x;
    if (i < N) {
        int r = exsc[i] + partials[blockIdx.x];
        exsc[i] = r;
        cursor[i] = r;
        no[i] = rsqrtf(fmaxf((float)degO[i], 1.0f));
        ni[i] = rsqrtf(fmaxf((float)degI[i], 1.0f));
    }
}

// ================= CSR fill: csr_src[slot(dst)] = src =================
__global__ __launch_bounds__(256) void fill_kernel(const int* __restrict__ src,
                                                   const int* __restrict__ dst,
                                                   int* cursor, int* csr_src, int E) {
    int e = blockIdx.x * 256 + threadIdx.x;
    if (e < E) {
        int pos = atomicAdd(&cursor[dst[e]], 1);
        csr_src[pos] = src[e];
    }
}

// ================= gather-aggregate: out[n] = sum_{e in(n)} h[src(e)] (*no[src]) =================
// Round 12: unroll x4 (was x2) — 4 independent row-gathers in flight per lane to
// hide ~600cyc L3 latency of random 512B-row reads.
template <int D4, int TPN, bool SCALE>
__global__ __launch_bounds__(256) void aggregate_kernel(const float4* __restrict__ h,
                                                        const int* __restrict__ row_start,
                                                        const int* __restrict__ deg,
                                                        const int* __restrict__ csr_src,
                                                        const float* __restrict__ no,
                                                        float4* __restrict__ out, int N) {
    int tid = blockIdx.x * 256 + threadIdx.x;
    int node = tid / TPN;
    int lane = tid % TPN;
    if (node >= N) return;
    const bool active = lane < D4;
    float4 acc = make_float4(0.f, 0.f, 0.f, 0.f);
    const int start = row_start[node];
    const int d = deg[node];
    int j = 0;
    for (; j + 3 < d; j += 4) {
        int s0 = csr_src[start + j];
        int s1 = csr_src[start + j + 1];
        int s2 = csr_src[start + j + 2];
        int s3 = csr_src[start + j + 3];
        if (active) {
            float4 v0 = h[(size_t)s0 * D4 + lane];
            float4 v1 = h[(size_t)s1 * D4 + lane];
            float4 v2 = h[(size_t)s2 * D4 + lane];
            float4 v3 = h[(size_t)s3 * D4 + lane];
            float c0 = SCALE ? no[s0] : 1.0f;
            float c1 = SCALE ? no[s1] : 1.0f;
            float c2 = SCALE ? no[s2] : 1.0f;
            float c3 = SCALE ? no[s3] : 1.0f;
            acc.x += v0.x * c0 + v1.x * c1 + v2.x * c2 + v3.x * c3;
            acc.y += v0.y * c0 + v1.y * c1 + v2.y * c2 + v3.y * c3;
            acc.z += v0.z * c0 + v1.z * c1 + v2.z * c2 + v3.z * c3;
            acc.w += v0.w * c0 + v1.w * c1 + v2.w * c2 + v3.w * c3;
        }
    }
    for (; j < d; ++j) {
        int s0 = csr_src[start + j];
        if (active) {
            float4 v0 = h[(size_t)s0 * D4 + lane];
            float c0 = SCALE ? no[s0] : 1.0f;
            acc.x += v0.x * c0;
            acc.y += v0.y * c0;
            acc.z += v0.z * c0;
            acc.w += v0.w * c0;
        }
    }
    if (active) out[(size_t)node * D4 + lane] = acc;
}

// ====== layer-3 fused aggregate (y is N x 48 dense): out[n,c<47] = relu(agg*nin + b3) ======
template <int D4, int TPN>
__global__ __launch_bounds__(256) void aggregate_final_kernel(const float4* __restrict__ y,
                                                              const int* __restrict__ row_start,
                                                              const int* __restrict__ deg,
                                                              const int* __restrict__ csr_src,
                                                              const float* __restrict__ nin,
                                                              const float* __restrict__ b3,
                                                              float* __restrict__ out, int N) {
    int tid = blockIdx.x * 256 + threadIdx.x;
    int node = tid / TPN;
    int lane = tid % TPN;
    if (node >= N) return;
    const bool active = lane < D4;
    float4 acc = make_float4(0.f, 0.f, 0.f, 0.f);
    const int start = row_start[node];
    const int d = deg[node];
    int j = 0;
    for (; j + 3 < d; j += 4) {
        int s0 = csr_src[start + j];
        int s1 = csr_src[start + j + 1];
        int s2 = csr_src[start + j + 2];
        int s3 = csr_src[start + j + 3];
        if (active) {
            float4 v0 = y[(size_t)s0 * D4 + lane];
            float4 v1 = y[(size_t)s1 * D4 + lane];
            float4 v2 = y[(size_t)s2 * D4 + lane];
            float4 v3 = y[(size_t)s3 * D4 + lane];
            acc.x += v0.x + v1.x + v2.x + v3.x;
            acc.y += v0.y + v1.y + v2.y + v3.y;
            acc.z += v0.z + v1.z + v2.z + v3.z;
            acc.w += v0.w + v1.w + v2.w + v3.w;
        }
    }
    for (; j < d; ++j) {
        int s0 = csr_src[start + j];
        if (active) {
            float4 v0 = y[(size_t)s0 * D4 + lane];
            acc.x += v0.x;
            acc.y += v0.y;
            acc.z += v0.z;
            acc.w += v0.w;
        }
    }
    if (active) {
        float s = nin[node];
        float vals[4] = {acc.x, acc.y, acc.z, acc.w};
        int c0 = lane * 4;
#pragma unroll
        for (int k = 0; k < 4; ++k) {
            int c = c0 + k;
            if (c < 47) out[(size_t)node * 47 + c] = fmaxf(vals[k] * s + b3[c], 0.0f);
        }
    }
}

// ================= GEMM: out = epi ? relu(A@W *nin + b)*nout : A@W =================
// FROZEN at round-7 shape — empirically the only non-spilling, best-measured
// config (76us, VGPR 60). Rounds 8/9/10/11 each perturbed one aspect (2-deep
// prefetch, LDS-A staging, launch_bounds(256,8), BK=32) and ALL spilled or
// regressed. Do not modify. ONLY <100,128,16> and <128,128,16> instantiations;
// layer 3 reuses <128,128,16> with runtime epi=0/ostride=48 (wcols=47 pads).
template <int K, int NOUTP, int TJ>
__global__ __launch_bounds__(256, 4) void gemm_kernel(const float* __restrict__ A,
                                                      const float* __restrict__ W, const int wcols,
                                                      const float* __restrict__ bias,
                                                      const float* __restrict__ nin,
                                                      const float* __restrict__ nout,
                                                      float* __restrict__ out, const int N,
                                                      const int epi, const int ostride) {
    constexpr int BK = 64;
    constexpr int ROWS = 256 / TJ;         // 16
    constexpr int M2 = 4;
    constexpr int BM = ROWS * M2;          // 64
    constexpr int NJ4 = NOUTP / (TJ * 4);  // 2
    constexpr int K4 = K / 4;
    constexpr int NCH = (K + BK - 1) / BK;

    __shared__ __align__(16) float Wl[BK * NOUTP];

    const int tid = threadIdx.x;
    const int tj = tid % TJ;
    const int r = tid / TJ;
    const int n0 = blockIdx.x * BM + r * M2;

    // clamped row pointers: invalid rows read row N-1 (garbage acc, never stored)
    const float4* pA[M2];
#pragma unroll
    for (int m = 0; m < M2; ++m) {
        int rm = n0 + m;
        rm = (rm < N) ? rm : (N - 1);
        pA[m] = (const float4*)A + (size_t)rm * K4;
    }

    float acc[M2][NJ4 * 4];
#pragma unroll
    for (int m = 0; m < M2; ++m)
#pragma unroll
        for (int j = 0; j < NJ4 * 4; ++j) acc[m][j] = 0.0f;

    // 1-deep register prefetch of A
    float4 an[M2];
#pragma unroll
    for (int m = 0; m < M2; ++m) an[m] = pA[m][0];

    for (int ch = 0; ch < NCH; ++ch) {
        const int k0 = ch * BK;
        const int L = (K - k0 < BK) ? (K - k0) : BK;
        if (wcols == NOUTP) {
            const float4* W4 = (const float4*)(W + (size_t)k0 * NOUTP);
            float4* Wl4 = (float4*)Wl;
            for (int i = tid; i < L * NOUTP / 4; i += 256) Wl4[i] = W4[i];
        } else {
            for (int i = tid; i < L * NOUTP; i += 256) {
                int k = i / NOUTP;
                int c = i - k * NOUTP;
                Wl[i] = (c < wcols) ? W[(size_t)(k0 + k) * wcols + c] : 0.0f;
            }
        }
        __syncthreads();

        const int L4 = L / 4;
        for (int k4 = 0; k4 < L4; ++k4) {
            float af[M2][4];
#pragma unroll
            for (int m = 0; m < M2; ++m) {
                af[m][0] = an[m].x; af[m][1] = an[m].y;
                af[m][2] = an[m].z; af[m][3] = an[m].w;
            }
            const int nk = k0 / 4 + k4 + 1;     // next global k4 (crosses chunk boundary)
            if (nk < K4) {
#pragma unroll
                for (int m = 0; m < M2; ++m) an[m] = pA[m][nk];
            }
#pragma unroll
            for (int kk = 0; kk < 4; ++kk) {
#pragma unroll
                for (int jj = 0; jj < NJ4; ++jj) {
                    const float4 w = *(const float4*)&Wl[(k4 * 4 + kk) * NOUTP + (jj * TJ + tj) * 4];
#pragma unroll
                    for (int m = 0; m < M2; ++m) {
                        acc[m][jj * 4 + 0] = fmaf(af[m][kk], w.x, acc[m][jj * 4 + 0]);
                        acc[m][jj * 4 + 1] = fmaf(af[m][kk], w.y, acc[m][jj * 4 + 1]);
                        acc[m][jj * 4 + 2] = fmaf(af[m][kk], w.z, acc[m][jj * 4 + 2]);
                        acc[m][jj * 4 + 3] = fmaf(af[m][kk], w.w, acc[m][jj * 4 + 3]);
                    }
                }
            }
        }
        __syncthreads();
    }

#pragma unroll
    for (int m = 0; m < M2; ++m) {
        const int n = n0 + m;
        if (n < N) {
            const float s_in = epi ? nin[n] : 1.0f;
            const float s_out = epi ? nout[n] : 1.0f;
#pragma unroll
            for (int jj = 0; jj < NJ4; ++jj) {
                const int c0 = (jj * TJ + tj) * 4;
                if (c0 < ostride) {
                    float v0e = acc[m][jj * 4 + 0] * s_in;
                    float v1e = acc[m][jj * 4 + 1] * s_in;
                    float v2e = acc[m][jj * 4 + 2] * s_in;
                    float v3e = acc[m][jj * 4 + 3] * s_in;
                    if (epi) {
                        v0e = fmaxf(v0e + bias[c0 + 0], 0.0f) * s_out;
                        v1e = fmaxf(v1e + bias[c0 + 1], 0.0f) * s_out;
                        v2e = fmaxf(v2e + bias[c0 + 2], 0.0f) * s_out;
                        v3e = fmaxf(v3e + bias[c0 + 3], 0.0f) * s_out;
                    }
                    float4 o = make_float4(v0e, v1e, v2e, v3e);
                    *(float4*)&out[(size_t)n * ostride + c0] = o;
                }
            }
        }
    }
}

extern "C" void kernel_launch(void* const* d_in, const int* in_sizes, int n_in,
                              void* d_out, int out_size, void* d_ws, size_t ws_size,
                              hipStream_t stream) {
    const float* x  = (const float*)d_in[0];
    const int*   ei = (const int*)d_in[1];
    const float* W1 = (const float*)d_in[2];
    const float* b1 = (const float*)d_in[3];
    const float* W2 = (const float*)d_in[4];
    const float* b2 = (const float*)d_in[5];
    const float* W3 = (const float*)d_in[6];
    const float* b3 = (const float*)d_in[7];
    float* out = (float*)d_out;

    const int N = NN;
    const int E = in_sizes[1] / 2;
    const int* src = ei;
    const int* dst = ei + E;

    // ---- workspace layout ----
    float* ws = (float*)d_ws;
    float* norm_out = ws;                       // N f
    float* norm_in  = ws + N;                   // N f
    float* bufA = ws + 2 * (size_t)N;           // N x 128 f (agg; aliased as bufY N x 48)
    float* bufB = bufA + (size_t)N * 128;       // N x 128 f (h)
    int* ip = (int*)(bufB + (size_t)N * 128);
    int* degO      = ip;                        // N i
    int* degI      = ip + N;                    // N i
    int* row_start = ip + 2 * (size_t)N;        // N i
    int* cursor    = ip + 3 * (size_t)N;        // N i
    int* csr_src   = ip + 4 * (size_t)N;        // E i
    int* partials  = csr_src + E;               // 512 i
    float* bufY = bufA;                         // N x 48 dense (layer-3 y)

    const int NB = (N + 255) / 256;             // 391 scan blocks

    // ---- degrees, norms, CSR ----
    hipMemsetAsync(degO, 0, 2 * (size_t)N * sizeof(int), stream);
    count_kernel<<<(E + 255) / 256, 256, 0, stream>>>(src, dst, degO, degI, E);
    scan1_kernel<<<NB, 256, 0, stream>>>(degI, row_start, partials, N);
    scan2_kernel<<<1, 512, 0, stream>>>(partials, NB);
    scan3_norm_kernel<<<NB, 256, 0, stream>>>(row_start, partials, cursor,
                                              degO, degI, norm_out, norm_in, N);
    fill_kernel<<<(E + 255) / 256, 256, 0, stream>>>(src, dst, cursor, csr_src, E);

    // ---- layer 1: agg1 = gather-agg(x * no, 100); h1' = relu(agg1@W1 *nin + b1) * no ----
    aggregate_kernel<25, 32, true><<<(N * 32 + 255) / 256, 256, 0, stream>>>(
        (const float4*)x, row_start, degI, csr_src, norm_out, (float4*)bufA, N);
    gemm_kernel<100, 128, 16><<<(N + 63) / 64, 256, 0, stream>>>(
        bufA, W1, 128, b1, norm_in, norm_out, bufB, N, 1, 128);

    // ---- layer 2: agg2 = gather-agg(h1', 128); h2' = relu(agg2@W2 *nin + b2) * no ----
    aggregate_kernel<32, 32, false><<<(N * 32 + 255) / 256, 256, 0, stream>>>(
        (const float4*)bufB, row_start, degI, csr_src, nullptr, (float4*)bufA, N);
    gemm_kernel<128, 128, 16><<<(N + 63) / 64, 256, 0, stream>>>(
        bufA, W2, 128, b2, norm_in, norm_out, bufB, N, 1, 128);

    // ---- layer 3 (reordered): y = h2'@W3 — SAME instantiation as layer 2, W3 cols
    //      zero-padded 47->128, compact output stride 48; then fused final aggregate ----
    gemm_kernel<128, 128, 16><<<(N + 63) / 64, 256, 0, stream>>>(
        bufB, W3, 47, nullptr, nullptr, nullptr, bufY, N, 0, 48);
    aggregate_final_kernel<12, 16><<<(N * 16 + 255) / 256, 256, 0, stream>>>(
        (const float4*)bufY, row_start, degI, csr_src, norm_in, b3, out, N);
}